// Round 1
// baseline (2963.046 us; speedup 1.0000x reference)
//
#include <hip/hip_runtime.h>
#include <hip/hip_bf16.h>

#define DD 1024
#define SS 1024
#define BB 2
#define HH 16
#define DFFN 4096
#define LLAYERS 2
#define RSTEPS 3
#define VV 32000
#define NTOK (BB*SS)

typedef __attribute__((ext_vector_type(8))) short s16x8;
typedef __attribute__((ext_vector_type(8))) __bf16 bf16x8;
typedef __attribute__((ext_vector_type(4))) float f32x4;

__device__ __forceinline__ unsigned short f2bf(float f) {
  unsigned int u = __float_as_uint(f);
  u += 0x7FFFu + ((u >> 16) & 1u);
  return (unsigned short)(u >> 16);
}

__device__ __forceinline__ f32x4 mfma16(s16x8 a, s16x8 b, f32x4 c) {
  return __builtin_amdgcn_mfma_f32_16x16x32_bf16(
      __builtin_bit_cast(bf16x8, a), __builtin_bit_cast(bf16x8, b), c, 0, 0, 0);
}

// ---------------- embed: res = token_embed[ids] + pos_embed ----------------
__global__ __launch_bounds__(256) void embed_kernel(
    const int* __restrict__ ids, const float* __restrict__ te,
    const float* __restrict__ pe, float* __restrict__ res) {
  int row = blockIdx.x;                 // 0..NTOK-1
  int s = row & (SS - 1);
  int id = ids[row];
  int d = threadIdx.x * 4;
  float4 a = *(const float4*)(te + (long)id * DD + d);
  float4 p = *(const float4*)(pe + (long)s * DD + d);
  float4 o; o.x = a.x + p.x; o.y = a.y + p.y; o.z = a.z + p.z; o.w = a.w + p.w;
  *(float4*)(res + (long)row * DD + d) = o;
}

// ---------------- router: logits, softmax probs, depth = argmax+1 ----------
__global__ __launch_bounds__(64) void router_kernel(
    const float* __restrict__ h, const float* __restrict__ Wr,
    const float* __restrict__ br, float* __restrict__ probs,
    float* __restrict__ depth_ws, float* __restrict__ out_depth) {
  int row = blockIdx.x;
  int lane = threadIdx.x;
  const float* hr = h + (long)row * DD;
  float a0 = 0.f, a1 = 0.f, a2 = 0.f;
  for (int i = 0; i < 16; ++i) {
    int d = lane * 16 + i;
    float hv = hr[d];
    a0 += hv * Wr[d * 3 + 0];
    a1 += hv * Wr[d * 3 + 1];
    a2 += hv * Wr[d * 3 + 2];
  }
  for (int off = 32; off; off >>= 1) {
    a0 += __shfl_down(a0, off);
    a1 += __shfl_down(a1, off);
    a2 += __shfl_down(a2, off);
  }
  if (lane == 0) {
    a0 += br[0]; a1 += br[1]; a2 += br[2];
    float m = fmaxf(a0, fmaxf(a1, a2));
    float e0 = expf(a0 - m), e1 = expf(a1 - m), e2 = expf(a2 - m);
    float inv = 1.f / (e0 + e1 + e2);
    probs[row * 3 + 0] = e0 * inv;
    probs[row * 3 + 1] = e1 * inv;
    probs[row * 3 + 2] = e2 * inv;
    int am = 0; float bv = a0;
    if (a1 > bv) { bv = a1; am = 1; }
    if (a2 > bv) { bv = a2; am = 2; }
    float dm = (float)(am + 1);
    depth_ws[row] = dm;
    out_depth[row] = dm;
  }
}

__global__ __launch_bounds__(256) void router_finalize_kernel(
    const float* __restrict__ probs, float* __restrict__ out_loss) {
  __shared__ float red[256][3];
  int t = threadIdx.x;
  float s0 = 0.f, s1 = 0.f, s2 = 0.f;
  for (int r = t; r < NTOK; r += 256) {
    s0 += probs[r * 3 + 0]; s1 += probs[r * 3 + 1]; s2 += probs[r * 3 + 2];
  }
  red[t][0] = s0; red[t][1] = s1; red[t][2] = s2;
  __syncthreads();
  for (int off = 128; off; off >>= 1) {
    if (t < off) {
      red[t][0] += red[t + off][0];
      red[t][1] += red[t + off][1];
      red[t][2] += red[t + off][2];
    }
    __syncthreads();
  }
  if (t == 0) {
    float i0 = red[0][0] / NTOK, i1 = red[0][1] / NTOK, i2 = red[0][2] / NTOK;
    out_loss[0] = (float)RSTEPS * (i0 * i0 + i1 * i1 + i2 * i2);
  }
}

// ---------------- layernorm: f32 in -> bf16 out ----------------------------
__global__ __launch_bounds__(256) void ln_kernel(
    const float* __restrict__ x, const float* __restrict__ g,
    const float* __restrict__ b, unsigned short* __restrict__ y) {
  int row = blockIdx.x;
  int t = threadIdx.x;
  float4 v = *(const float4*)(x + (long)row * DD + t * 4);
  float s = v.x + v.y + v.z + v.w;
  float q = v.x * v.x + v.y * v.y + v.z * v.z + v.w * v.w;
  for (int off = 32; off; off >>= 1) {
    s += __shfl_down(s, off);
    q += __shfl_down(q, off);
  }
  __shared__ float rs[4], rq[4];
  int wave = t >> 6;
  if ((t & 63) == 0) { rs[wave] = s; rq[wave] = q; }
  __syncthreads();
  float S_ = rs[0] + rs[1] + rs[2] + rs[3];
  float Q_ = rq[0] + rq[1] + rq[2] + rq[3];
  float mu = S_ * (1.f / DD);
  float var = Q_ * (1.f / DD) - mu * mu;
  float rstd = rsqrtf(var + 1e-5f);
  int d = t * 4;
  float4 gg = *(const float4*)(g + d);
  float4 bb = *(const float4*)(b + d);
  ushort4 ov;
  ov.x = f2bf((v.x - mu) * rstd * gg.x + bb.x);
  ov.y = f2bf((v.y - mu) * rstd * gg.y + bb.y);
  ov.z = f2bf((v.z - mu) * rstd * gg.z + bb.z);
  ov.w = f2bf((v.w - mu) * rstd * gg.w + bb.w);
  *(ushort4*)(y + (long)row * DD + d) = ov;
}

// ---------------- GEMM: C[M,N] = act(A_bf16[M,K] @ B_f32 + bias + resid) ----
// BNT=0: B stored [K][N]; BNT=1: B stored [N][K]. B converted f32->bf16 in staging.
// 64x64 tile, BK=64, 4 waves, each wave 32x32 (2x2 of 16x16x32 MFMA frags).
template<int CBF16, int BNT, int BIAS, int RESID, int GELU_ACT>
__global__ __launch_bounds__(256) void gemm_kernel(
    const unsigned short* __restrict__ A, int lda,
    const float* __restrict__ B, int ldb,
    void* __restrict__ Cv, int ldc,
    const float* __restrict__ bias,
    const float* __restrict__ resid, int ldr,
    int K) {
  __shared__ unsigned short As[64][72];
  __shared__ unsigned short Bt[64][72];   // Bt[n][k]
  const int tid = threadIdx.x;
  const int lane = tid & 63, wave = tid >> 6;
  const int g = lane >> 4, l16 = lane & 15;
  const int wr = wave >> 1, wc = wave & 1;
  const long m0 = (long)blockIdx.y * 64, n0 = (long)blockIdx.x * 64;
  f32x4 acc[2][2] = {};
  for (int k0 = 0; k0 < K; k0 += 64) {
    __syncthreads();
#pragma unroll
    for (int c = 0; c < 2; ++c) {
      int p = tid + c * 256;
      int r = p >> 3, kq = (p & 7) * 8;
      *(s16x8*)&As[r][kq] = *(const s16x8*)(A + (m0 + r) * lda + k0 + kq);
    }
#pragma unroll
    for (int c = 0; c < 2; ++c) {
      int p = tid + c * 256;
      if (BNT) {
        int r = p >> 3, kq = (p & 7) * 8;
        const float* src = B + (n0 + r) * (long)ldb + k0 + kq;
        float4 v0 = *(const float4*)src;
        float4 v1 = *(const float4*)(src + 4);
        unsigned short* dst = &Bt[r][kq];
        dst[0] = f2bf(v0.x); dst[1] = f2bf(v0.y); dst[2] = f2bf(v0.z); dst[3] = f2bf(v0.w);
        dst[4] = f2bf(v1.x); dst[5] = f2bf(v1.y); dst[6] = f2bf(v1.z); dst[7] = f2bf(v1.w);
      } else {
        int kr = p >> 3, nq = (p & 7) * 8;
        const float* src = B + (long)(k0 + kr) * ldb + n0 + nq;
        float4 v0 = *(const float4*)src;
        float4 v1 = *(const float4*)(src + 4);
        Bt[nq + 0][kr] = f2bf(v0.x); Bt[nq + 1][kr] = f2bf(v0.y);
        Bt[nq + 2][kr] = f2bf(v0.z); Bt[nq + 3][kr] = f2bf(v0.w);
        Bt[nq + 4][kr] = f2bf(v1.x); Bt[nq + 5][kr] = f2bf(v1.y);
        Bt[nq + 6][kr] = f2bf(v1.z); Bt[nq + 7][kr] = f2bf(v1.w);
      }
    }
    __syncthreads();
#pragma unroll
    for (int kk = 0; kk < 2; ++kk) {
      s16x8 bfr[2];
#pragma unroll
      for (int n = 0; n < 2; ++n)
        bfr[n] = *(const s16x8*)&Bt[wc * 32 + n * 16 + l16][kk * 32 + g * 8];
#pragma unroll
      for (int m = 0; m < 2; ++m) {
        s16x8 afr = *(const s16x8*)&As[wr * 32 + m * 16 + l16][kk * 32 + g * 8];
#pragma unroll
        for (int n = 0; n < 2; ++n)
          acc[m][n] = mfma16(afr, bfr[n], acc[m][n]);
      }
    }
  }
  // epilogue: C/D layout col=lane&15, row=(lane>>4)*4+r
#pragma unroll
  for (int m = 0; m < 2; ++m) {
#pragma unroll
    for (int n = 0; n < 2; ++n) {
      long row_base = m0 + wr * 32 + m * 16 + g * 4;
      long col = n0 + wc * 32 + n * 16 + l16;
      float bv = BIAS ? bias[col] : 0.f;
#pragma unroll
      for (int r = 0; r < 4; ++r) {
        long row = row_base + r;
        float v = acc[m][n][r] + bv;
        if (RESID) v += resid[row * (long)ldr + col];
        if (GELU_ACT) {
          float x3 = v * v * v;
          v = 0.5f * v * (1.f + tanhf(0.7978845608028654f * (v + 0.044715f * x3)));
        }
        if (CBF16) ((unsigned short*)Cv)[row * (long)ldc + col] = f2bf(v);
        else       ((float*)Cv)[row * (long)ldc + col] = v;
      }
    }
  }
}

// ---------------- flash attention (causal), HD=64, bf16 in/out -------------
// block = 256 thr = 4 waves; each wave owns 16 q-rows; KV tiles of 32 shared via LDS.
__global__ __launch_bounds__(256) void attn_kernel(
    const unsigned short* __restrict__ qkv,  // [NTOK][3072]
    unsigned short* __restrict__ o) {        // [NTOK][1024]
  const int qb = blockIdx.x;   // S/64
  const int bh = blockIdx.y;   // B*H
  const int b = bh >> 4, h = bh & 15;
  const int tid = threadIdx.x, wave = tid >> 6, lane = tid & 63;
  const int g = lane >> 4, l16 = lane & 15;
  __shared__ unsigned short Kt[32][72];      // [kv][d]
  __shared__ unsigned short Vt[64][40];      // [d][kv]  (transposed)
  __shared__ unsigned short Pl[4][16][40];   // per-wave P relayout scratch
  const float NEG_INF = -__builtin_inff();
  const int q0 = qb * 64;
  const int qrw = q0 + wave * 16;
  const long rowbase = (long)b * SS;
  const unsigned short* qptr = qkv + (rowbase + qrw + l16) * 3072 + h * 64;
  s16x8 qf0 = *(const s16x8*)(qptr + g * 8);
  s16x8 qf1 = *(const s16x8*)(qptr + 32 + g * 8);
  f32x4 oacc[4] = {};
  float mrun[4], lrun[4];
#pragma unroll
  for (int r = 0; r < 4; ++r) { mrun[r] = NEG_INF; lrun[r] = 0.f; }
  const int ntile = q0 / 32 + 2;
  for (int t = 0; t < ntile; ++t) {
    const int kv0 = t * 32;
    __syncthreads();
    {
      int kv = tid >> 3, dq = (tid & 7) * 8;
      const unsigned short* ksrc = qkv + (rowbase + kv0 + kv) * 3072 + 1024 + h * 64 + dq;
      *(s16x8*)&Kt[kv][dq] = *(const s16x8*)ksrc;
      const unsigned short* vsrc = qkv + (rowbase + kv0 + kv) * 3072 + 2048 + h * 64 + dq;
      s16x8 vv = *(const s16x8*)vsrc;
#pragma unroll
      for (int j = 0; j < 8; ++j) Vt[dq + j][kv] = vv[j];
    }
    __syncthreads();
    // S = Q @ K^T  (M=16 rows, N=32 kv (2 frags), K=64 d (2 steps))
    f32x4 sfr[2] = {};
#pragma unroll
    for (int n = 0; n < 2; ++n) {
      s16x8 k0f = *(const s16x8*)&Kt[n * 16 + l16][g * 8];
      s16x8 k1f = *(const s16x8*)&Kt[n * 16 + l16][32 + g * 8];
      sfr[n] = mfma16(qf0, k0f, sfr[n]);
      sfr[n] = mfma16(qf1, k1f, sfr[n]);
    }
    // scale + causal mask; online softmax (row = (g*4+r), col = l16)
    float tv[2][4];
#pragma unroll
    for (int n = 0; n < 2; ++n) {
      int kj = kv0 + n * 16 + l16;
#pragma unroll
      for (int r = 0; r < 4; ++r) {
        int qi = qrw + g * 4 + r;
        tv[n][r] = (kj <= qi) ? sfr[n][r] * 0.125f : NEG_INF;
      }
    }
#pragma unroll
    for (int r = 0; r < 4; ++r) {
      float mx = fmaxf(tv[0][r], tv[1][r]);
      mx = fmaxf(mx, __shfl_xor(mx, 1));
      mx = fmaxf(mx, __shfl_xor(mx, 2));
      mx = fmaxf(mx, __shfl_xor(mx, 4));
      mx = fmaxf(mx, __shfl_xor(mx, 8));
      float mnew = fmaxf(mrun[r], mx);
      float alpha = __expf(mrun[r] - mnew);
      float p0 = __expf(tv[0][r] - mnew);
      float p1 = __expf(tv[1][r] - mnew);
      float rs_ = p0 + p1;
      rs_ += __shfl_xor(rs_, 1);
      rs_ += __shfl_xor(rs_, 2);
      rs_ += __shfl_xor(rs_, 4);
      rs_ += __shfl_xor(rs_, 8);
      lrun[r] = lrun[r] * alpha + rs_;
      mrun[r] = mnew;
#pragma unroll
      for (int nd = 0; nd < 4; ++nd) oacc[nd][r] *= alpha;
      Pl[wave][g * 4 + r][l16] = f2bf(p0);
      Pl[wave][g * 4 + r][16 + l16] = f2bf(p1);
    }
    __syncthreads();
    // O += P @ V   (A-frag: row=l16, k=kv=(g*8+j); B-frag: Vt[d][kv])
    s16x8 pa = *(const s16x8*)&Pl[wave][l16][g * 8];
#pragma unroll
    for (int nd = 0; nd < 4; ++nd) {
      s16x8 vf = *(const s16x8*)&Vt[nd * 16 + l16][g * 8];
      oacc[nd] = mfma16(pa, vf, oacc[nd]);
    }
  }
  unsigned short* obase = o + (rowbase + qrw) * 1024 + h * 64;
#pragma unroll
  for (int r = 0; r < 4; ++r) {
    float inv = 1.f / lrun[r];
#pragma unroll
    for (int nd = 0; nd < 4; ++nd)
      obase[(long)(g * 4 + r) * 1024 + nd * 16 + l16] = f2bf(oacc[nd][r] * inv);
  }
}

// ---------------- select: res = depth>=step+1 ? x : res --------------------
__global__ __launch_bounds__(256) void select_kernel(
    float* __restrict__ res, const float* __restrict__ x,
    const float* __restrict__ depth_ws, int step1) {
  long i = (long)blockIdx.x * blockDim.x + threadIdx.x;  // float4 index
  int tok = (int)(i >> 8);                               // 256 float4 per token
  if (depth_ws[tok] >= (float)step1)
    ((float4*)res)[i] = ((const float4*)x)[i];
}

extern "C" void kernel_launch(void* const* d_in, const int* in_sizes, int n_in,
                              void* d_out, int out_size, void* d_ws, size_t ws_size,
                              hipStream_t stream) {
  (void)in_sizes; (void)n_in; (void)out_size; (void)ws_size;
  const int*   ids  = (const int*)d_in[0];
  const float* te   = (const float*)d_in[1];
  const float* pe   = (const float*)d_in[2];
  const float* Wqkv = (const float*)d_in[3];
  const float* bqkv = (const float*)d_in[4];
  const float* Wo   = (const float*)d_in[5];
  const float* bo   = (const float*)d_in[6];
  const float* W1   = (const float*)d_in[7];
  const float* b1   = (const float*)d_in[8];
  const float* W2   = (const float*)d_in[9];
  const float* b2   = (const float*)d_in[10];
  const float* ln1g = (const float*)d_in[11];
  const float* ln1b = (const float*)d_in[12];
  const float* ln2g = (const float*)d_in[13];
  const float* ln2b = (const float*)d_in[14];
  const float* fing = (const float*)d_in[15];
  const float* finb = (const float*)d_in[16];
  const float* Wr   = (const float*)d_in[17];
  const float* br   = (const float*)d_in[18];

  float* logits    = (float*)d_out;
  float* out_depth = logits + (long)NTOK * VV;
  float* out_loss  = out_depth + NTOK;

  char* w = (char*)d_ws;
  float* res            = (float*)w;          w += (long)NTOK * DD * 4;
  float* x              = (float*)w;          w += (long)NTOK * DD * 4;
  unsigned short* hbuf  = (unsigned short*)w; w += (long)NTOK * DD * 2;
  unsigned short* qkvb  = (unsigned short*)w; w += (long)NTOK * 3 * DD * 2;
  unsigned short* obuf  = (unsigned short*)w; w += (long)NTOK * DD * 2;
  unsigned short* ffn1  = (unsigned short*)w; w += (long)NTOK * DFFN * 2;
  float* probs          = (float*)w;          w += (long)NTOK * 3 * 4;
  float* depth_ws       = (float*)w;          w += (long)NTOK * 4;

  embed_kernel<<<NTOK, 256, 0, stream>>>(ids, te, pe, res);
  router_kernel<<<NTOK, 64, 0, stream>>>(res, Wr, br, probs, depth_ws, out_depth);
  router_finalize_kernel<<<1, 256, 0, stream>>>(probs, out_loss);

  for (int step = 0; step < RSTEPS; ++step) {
    hipMemcpyAsync(x, res, (size_t)NTOK * DD * 4, hipMemcpyDeviceToDevice, stream);
    for (int l = 0; l < LLAYERS; ++l) {
      ln_kernel<<<NTOK, 256, 0, stream>>>(x, ln1g + l * DD, ln1b + l * DD, hbuf);
      gemm_kernel<1, 0, 1, 0, 0><<<dim3(3 * DD / 64, NTOK / 64), 256, 0, stream>>>(
          hbuf, DD, Wqkv + (long)l * DD * 3 * DD, 3 * DD, qkvb, 3 * DD,
          bqkv + (long)l * 3 * DD, nullptr, 0, DD);
      attn_kernel<<<dim3(SS / 64, BB * HH), 256, 0, stream>>>(qkvb, obuf);
      gemm_kernel<0, 0, 1, 1, 0><<<dim3(DD / 64, NTOK / 64), 256, 0, stream>>>(
          obuf, DD, Wo + (long)l * DD * DD, DD, x, DD,
          bo + (long)l * DD, x, DD, DD);
      ln_kernel<<<NTOK, 256, 0, stream>>>(x, ln2g + l * DD, ln2b + l * DD, hbuf);
      gemm_kernel<1, 0, 1, 0, 1><<<dim3(DFFN / 64, NTOK / 64), 256, 0, stream>>>(
          hbuf, DD, W1 + (long)l * DD * DFFN, DFFN, ffn1, DFFN,
          b1 + (long)l * DFFN, nullptr, 0, DD);
      gemm_kernel<0, 0, 1, 1, 0><<<dim3(DD / 64, NTOK / 64), 256, 0, stream>>>(
          ffn1, DFFN, W2 + (long)l * DFFN * DD, DD, x, DD,
          b2 + (long)l * DD, x, DD, DFFN);
    }
    select_kernel<<<2048, 256, 0, stream>>>(res, x, depth_ws, step + 1);
  }
  ln_kernel<<<NTOK, 256, 0, stream>>>(res, fing, finb, hbuf);
  gemm_kernel<0, 1, 0, 0, 0><<<dim3(VV / 64, NTOK / 64), 256, 0, stream>>>(
      hbuf, DD, te, DD, logits, VV, nullptr, nullptr, 0, DD);
}

// Round 2
// 1708.846 us; speedup vs baseline: 1.7339x; 1.7339x over previous
//
#include <hip/hip_runtime.h>
#include <hip/hip_bf16.h>

#define DD 1024
#define SS 1024
#define BB 2
#define HH 16
#define DFFN 4096
#define LLAYERS 2
#define RSTEPS 3
#define VV 32000
#define NTOK (BB*SS)

typedef __attribute__((ext_vector_type(8))) short s16x8;
typedef __attribute__((ext_vector_type(8))) __bf16 bf16x8;
typedef __attribute__((ext_vector_type(4))) float f32x4;

__device__ __forceinline__ unsigned short f2bf(float f) {
  unsigned int u = __float_as_uint(f);
  u += 0x7FFFu + ((u >> 16) & 1u);
  return (unsigned short)(u >> 16);
}

__device__ __forceinline__ f32x4 mfma16(s16x8 a, s16x8 b, f32x4 c) {
  return __builtin_amdgcn_mfma_f32_16x16x32_bf16(
      __builtin_bit_cast(bf16x8, a), __builtin_bit_cast(bf16x8, b), c, 0, 0, 0);
}

__device__ __forceinline__ void gload16(const unsigned short* g, unsigned short* l) {
  __builtin_amdgcn_global_load_lds(
      (const __attribute__((address_space(1))) unsigned int*)(const void*)g,
      (__attribute__((address_space(3))) unsigned int*)(void*)l, 16, 0, 0);
}

// ---------------- weight prep: f32 [K][N] -> bf16 [N][K] -------------------
__global__ __launch_bounds__(256) void wtrans_kernel(
    const float* __restrict__ src, unsigned short* __restrict__ dst,
    int Kd, int Nd) {
  __shared__ unsigned short t[64][68];
  const int n0 = blockIdx.x * 64, k0 = blockIdx.y * 64;
  const int tid = threadIdx.x;
#pragma unroll
  for (int c = 0; c < 4; ++c) {
    int p = tid + c * 256;
    int kr = p >> 4, nc = (p & 15) * 4;
    float4 v = *(const float4*)(src + (long)(k0 + kr) * Nd + n0 + nc);
    t[nc + 0][kr] = f2bf(v.x);
    t[nc + 1][kr] = f2bf(v.y);
    t[nc + 2][kr] = f2bf(v.z);
    t[nc + 3][kr] = f2bf(v.w);
  }
  __syncthreads();
#pragma unroll
  for (int c = 0; c < 4; ++c) {
    int p = tid + c * 256;
    int nr = p >> 4, kc = (p & 15) * 4;
    ushort4 o;
    o.x = t[nr][kc]; o.y = t[nr][kc + 1]; o.z = t[nr][kc + 2]; o.w = t[nr][kc + 3];
    *(ushort4*)(dst + (long)(n0 + nr) * Kd + k0 + kc) = o;
  }
}

// ---------------- f32 -> bf16 straight convert (te) ------------------------
__global__ __launch_bounds__(256) void bconv_kernel(
    const float* __restrict__ src, unsigned short* __restrict__ dst) {
  long i = ((long)blockIdx.x * 256 + threadIdx.x) * 8;
  float4 v0 = *(const float4*)(src + i);
  float4 v1 = *(const float4*)(src + i + 4);
  ushort4 a, b;
  a.x = f2bf(v0.x); a.y = f2bf(v0.y); a.z = f2bf(v0.z); a.w = f2bf(v0.w);
  b.x = f2bf(v1.x); b.y = f2bf(v1.y); b.z = f2bf(v1.z); b.w = f2bf(v1.w);
  *(ushort4*)(dst + i) = a;
  *(ushort4*)(dst + i + 4) = b;
}

// ---------------- embed: res = token_embed[ids] + pos_embed ----------------
__global__ __launch_bounds__(256) void embed_kernel(
    const int* __restrict__ ids, const float* __restrict__ te,
    const float* __restrict__ pe, float* __restrict__ res) {
  int row = blockIdx.x;
  int s = row & (SS - 1);
  int id = ids[row];
  int d = threadIdx.x * 4;
  float4 a = *(const float4*)(te + (long)id * DD + d);
  float4 p = *(const float4*)(pe + (long)s * DD + d);
  float4 o; o.x = a.x + p.x; o.y = a.y + p.y; o.z = a.z + p.z; o.w = a.w + p.w;
  *(float4*)(res + (long)row * DD + d) = o;
}

// ---------------- router ---------------------------------------------------
__global__ __launch_bounds__(64) void router_kernel(
    const float* __restrict__ h, const float* __restrict__ Wr,
    const float* __restrict__ br, float* __restrict__ probs,
    float* __restrict__ depth_ws, float* __restrict__ out_depth) {
  int row = blockIdx.x;
  int lane = threadIdx.x;
  const float* hr = h + (long)row * DD;
  float a0 = 0.f, a1 = 0.f, a2 = 0.f;
  for (int i = 0; i < 16; ++i) {
    int d = lane * 16 + i;
    float hv = hr[d];
    a0 += hv * Wr[d * 3 + 0];
    a1 += hv * Wr[d * 3 + 1];
    a2 += hv * Wr[d * 3 + 2];
  }
  for (int off = 32; off; off >>= 1) {
    a0 += __shfl_down(a0, off);
    a1 += __shfl_down(a1, off);
    a2 += __shfl_down(a2, off);
  }
  if (lane == 0) {
    a0 += br[0]; a1 += br[1]; a2 += br[2];
    float m = fmaxf(a0, fmaxf(a1, a2));
    float e0 = expf(a0 - m), e1 = expf(a1 - m), e2 = expf(a2 - m);
    float inv = 1.f / (e0 + e1 + e2);
    probs[row * 3 + 0] = e0 * inv;
    probs[row * 3 + 1] = e1 * inv;
    probs[row * 3 + 2] = e2 * inv;
    int am = 0; float bv = a0;
    if (a1 > bv) { bv = a1; am = 1; }
    if (a2 > bv) { bv = a2; am = 2; }
    float dm = (float)(am + 1);
    depth_ws[row] = dm;
    out_depth[row] = dm;
  }
}

__global__ __launch_bounds__(256) void router_finalize_kernel(
    const float* __restrict__ probs, float* __restrict__ out_loss) {
  __shared__ float red[256][3];
  int t = threadIdx.x;
  float s0 = 0.f, s1 = 0.f, s2 = 0.f;
  for (int r = t; r < NTOK; r += 256) {
    s0 += probs[r * 3 + 0]; s1 += probs[r * 3 + 1]; s2 += probs[r * 3 + 2];
  }
  red[t][0] = s0; red[t][1] = s1; red[t][2] = s2;
  __syncthreads();
  for (int off = 128; off; off >>= 1) {
    if (t < off) {
      red[t][0] += red[t + off][0];
      red[t][1] += red[t + off][1];
      red[t][2] += red[t + off][2];
    }
    __syncthreads();
  }
  if (t == 0) {
    float i0 = red[0][0] / NTOK, i1 = red[0][1] / NTOK, i2 = red[0][2] / NTOK;
    out_loss[0] = (float)RSTEPS * (i0 * i0 + i1 * i1 + i2 * i2);
  }
}

// ---------------- layernorm: f32 in -> bf16 out ----------------------------
__global__ __launch_bounds__(256) void ln_kernel(
    const float* __restrict__ x, const float* __restrict__ g,
    const float* __restrict__ b, unsigned short* __restrict__ y) {
  int row = blockIdx.x;
  int t = threadIdx.x;
  float4 v = *(const float4*)(x + (long)row * DD + t * 4);
  float s = v.x + v.y + v.z + v.w;
  float q = v.x * v.x + v.y * v.y + v.z * v.z + v.w * v.w;
  for (int off = 32; off; off >>= 1) {
    s += __shfl_down(s, off);
    q += __shfl_down(q, off);
  }
  __shared__ float rs[4], rq[4];
  int wave = t >> 6;
  if ((t & 63) == 0) { rs[wave] = s; rq[wave] = q; }
  __syncthreads();
  float S_ = rs[0] + rs[1] + rs[2] + rs[3];
  float Q_ = rq[0] + rq[1] + rq[2] + rq[3];
  float mu = S_ * (1.f / DD);
  float var = Q_ * (1.f / DD) - mu * mu;
  float rstd = rsqrtf(var + 1e-5f);
  int d = t * 4;
  float4 gg = *(const float4*)(g + d);
  float4 bb = *(const float4*)(b + d);
  ushort4 ov;
  ov.x = f2bf((v.x - mu) * rstd * gg.x + bb.x);
  ov.y = f2bf((v.y - mu) * rstd * gg.y + bb.y);
  ov.z = f2bf((v.z - mu) * rstd * gg.z + bb.z);
  ov.w = f2bf((v.w - mu) * rstd * gg.w + bb.w);
  *(ushort4*)(y + (long)row * DD + d) = ov;
}

// ---------------- GEMM (m97 structure): 128 x BN tile, BK=64 ---------------
// A bf16 [M][K], Bt bf16 [N][K]; 4 waves in 2x2, each computes 64 x BN/2.
template<int BN, int CBF16, int BIAS, int RESID, int GELU_ACT>
__global__ __launch_bounds__(256) void gemm128_kernel(
    const unsigned short* __restrict__ A, int lda,
    const unsigned short* __restrict__ Bt, int ldb,
    void* __restrict__ Cv, int ldc,
    const float* __restrict__ bias,
    const float* __restrict__ resid, int ldr,
    int K) {
  constexpr int BM = 128;
  constexpr int WN = BN / 2;
  constexpr int MR = 4;
  constexpr int NR = WN / 16;
  __shared__ unsigned short As[BM * 64];
  __shared__ unsigned short Bs[BN * 64];
  const int tid = threadIdx.x;
  const int lane = tid & 63, wave = tid >> 6;
  const int g = lane >> 4, l16 = lane & 15;
  const int wr = wave >> 1, wc = wave & 1;
  const long m0 = (long)blockIdx.y * BM, n0 = (long)blockIdx.x * BN;
  f32x4 acc[MR][NR] = {};
  for (int k0 = 0; k0 < K; k0 += 64) {
    __syncthreads();
#pragma unroll
    for (int c = 0; c < BM / 32; ++c) {
      int p = tid + c * 256;
      int r = p >> 3, kq = (p & 7) * 8;
      gload16(A + (m0 + r) * (long)lda + k0 + kq, &As[p * 8]);
    }
#pragma unroll
    for (int c = 0; c < BN / 32; ++c) {
      int p = tid + c * 256;
      int r = p >> 3, kq = (p & 7) * 8;
      gload16(Bt + (n0 + r) * (long)ldb + k0 + kq, &Bs[p * 8]);
    }
    __syncthreads();
#pragma unroll
    for (int kk = 0; kk < 2; ++kk) {
      s16x8 af[MR], bf[NR];
#pragma unroll
      for (int m = 0; m < MR; ++m)
        af[m] = *(const s16x8*)&As[(wr * 64 + m * 16 + l16) * 64 + kk * 32 + g * 8];
#pragma unroll
      for (int n = 0; n < NR; ++n)
        bf[n] = *(const s16x8*)&Bs[(wc * WN + n * 16 + l16) * 64 + kk * 32 + g * 8];
#pragma unroll
      for (int m = 0; m < MR; ++m)
#pragma unroll
        for (int n = 0; n < NR; ++n)
          acc[m][n] = mfma16(af[m], bf[n], acc[m][n]);
    }
  }
  // epilogue: C/D layout col=lane&15, row=(lane>>4)*4+r
#pragma unroll
  for (int m = 0; m < MR; ++m) {
#pragma unroll
    for (int n = 0; n < NR; ++n) {
      long row_base = m0 + wr * 64 + m * 16 + g * 4;
      long col = n0 + wc * WN + n * 16 + l16;
      float bv = BIAS ? bias[col] : 0.f;
#pragma unroll
      for (int r = 0; r < 4; ++r) {
        long row = row_base + r;
        float v = acc[m][n][r] + bv;
        if (RESID) v += resid[row * (long)ldr + col];
        if (GELU_ACT) {
          float x3 = v * v * v;
          v = 0.5f * v * (1.f + tanhf(0.7978845608028654f * (v + 0.044715f * x3)));
        }
        if (CBF16) ((unsigned short*)Cv)[row * (long)ldc + col] = f2bf(v);
        else       ((float*)Cv)[row * (long)ldc + col] = v;
      }
    }
  }
}

// ---------------- flash attention (causal), HD=64, bf16 in/out -------------
__global__ __launch_bounds__(256) void attn_kernel(
    const unsigned short* __restrict__ qkv,  // [NTOK][3072]
    unsigned short* __restrict__ o) {        // [NTOK][1024]
  const int qb = blockIdx.x;
  const int bh = blockIdx.y;
  const int b = bh >> 4, h = bh & 15;
  const int tid = threadIdx.x, wave = tid >> 6, lane = tid & 63;
  const int g = lane >> 4, l16 = lane & 15;
  __shared__ unsigned short Kt[32][72];
  __shared__ unsigned short Vt[64][40];
  __shared__ unsigned short Pl[4][16][40];
  const float NEG_INF = -__builtin_inff();
  const int q0 = qb * 64;
  const int qrw = q0 + wave * 16;
  const long rowbase = (long)b * SS;
  const unsigned short* qptr = qkv + (rowbase + qrw + l16) * 3072 + h * 64;
  s16x8 qf0 = *(const s16x8*)(qptr + g * 8);
  s16x8 qf1 = *(const s16x8*)(qptr + 32 + g * 8);
  f32x4 oacc[4] = {};
  float mrun[4], lrun[4];
#pragma unroll
  for (int r = 0; r < 4; ++r) { mrun[r] = NEG_INF; lrun[r] = 0.f; }
  const int ntile = q0 / 32 + 2;
  for (int t = 0; t < ntile; ++t) {
    const int kv0 = t * 32;
    __syncthreads();
    {
      int kv = tid >> 3, dq = (tid & 7) * 8;
      const unsigned short* ksrc = qkv + (rowbase + kv0 + kv) * 3072 + 1024 + h * 64 + dq;
      *(s16x8*)&Kt[kv][dq] = *(const s16x8*)ksrc;
      const unsigned short* vsrc = qkv + (rowbase + kv0 + kv) * 3072 + 2048 + h * 64 + dq;
      s16x8 vv = *(const s16x8*)vsrc;
#pragma unroll
      for (int j = 0; j < 8; ++j) Vt[dq + j][kv] = vv[j];
    }
    __syncthreads();
    f32x4 sfr[2] = {};
#pragma unroll
    for (int n = 0; n < 2; ++n) {
      s16x8 k0f = *(const s16x8*)&Kt[n * 16 + l16][g * 8];
      s16x8 k1f = *(const s16x8*)&Kt[n * 16 + l16][32 + g * 8];
      sfr[n] = mfma16(qf0, k0f, sfr[n]);
      sfr[n] = mfma16(qf1, k1f, sfr[n]);
    }
    float tv[2][4];
#pragma unroll
    for (int n = 0; n < 2; ++n) {
      int kj = kv0 + n * 16 + l16;
#pragma unroll
      for (int r = 0; r < 4; ++r) {
        int qi = qrw + g * 4 + r;
        tv[n][r] = (kj <= qi) ? sfr[n][r] * 0.125f : NEG_INF;
      }
    }
#pragma unroll
    for (int r = 0; r < 4; ++r) {
      float mx = fmaxf(tv[0][r], tv[1][r]);
      mx = fmaxf(mx, __shfl_xor(mx, 1));
      mx = fmaxf(mx, __shfl_xor(mx, 2));
      mx = fmaxf(mx, __shfl_xor(mx, 4));
      mx = fmaxf(mx, __shfl_xor(mx, 8));
      float mnew = fmaxf(mrun[r], mx);
      float alpha = __expf(mrun[r] - mnew);
      float p0 = __expf(tv[0][r] - mnew);
      float p1 = __expf(tv[1][r] - mnew);
      float rs_ = p0 + p1;
      rs_ += __shfl_xor(rs_, 1);
      rs_ += __shfl_xor(rs_, 2);
      rs_ += __shfl_xor(rs_, 4);
      rs_ += __shfl_xor(rs_, 8);
      lrun[r] = lrun[r] * alpha + rs_;
      mrun[r] = mnew;
#pragma unroll
      for (int nd = 0; nd < 4; ++nd) oacc[nd][r] *= alpha;
      Pl[wave][g * 4 + r][l16] = f2bf(p0);
      Pl[wave][g * 4 + r][16 + l16] = f2bf(p1);
    }
    __syncthreads();
    s16x8 pa = *(const s16x8*)&Pl[wave][l16][g * 8];
#pragma unroll
    for (int nd = 0; nd < 4; ++nd) {
      s16x8 vf = *(const s16x8*)&Vt[nd * 16 + l16][g * 8];
      oacc[nd] = mfma16(pa, vf, oacc[nd]);
    }
  }
  unsigned short* obase = o + (rowbase + qrw) * 1024 + h * 64;
#pragma unroll
  for (int r = 0; r < 4; ++r) {
    float inv = 1.f / lrun[r];
#pragma unroll
    for (int nd = 0; nd < 4; ++nd)
      obase[(long)(g * 4 + r) * 1024 + nd * 16 + l16] = f2bf(oacc[nd][r] * inv);
  }
}

// ---------------- select: res = depth>=step+1 ? x : res --------------------
__global__ __launch_bounds__(256) void select_kernel(
    float* __restrict__ res, const float* __restrict__ x,
    const float* __restrict__ depth_ws, int step1) {
  long i = (long)blockIdx.x * blockDim.x + threadIdx.x;
  int tok = (int)(i >> 8);
  if (depth_ws[tok] >= (float)step1)
    ((float4*)res)[i] = ((const float4*)x)[i];
}

extern "C" void kernel_launch(void* const* d_in, const int* in_sizes, int n_in,
                              void* d_out, int out_size, void* d_ws, size_t ws_size,
                              hipStream_t stream) {
  (void)in_sizes; (void)n_in; (void)out_size; (void)ws_size;
  const int*   ids  = (const int*)d_in[0];
  const float* te   = (const float*)d_in[1];
  const float* pe   = (const float*)d_in[2];
  const float* Wqkv = (const float*)d_in[3];
  const float* bqkv = (const float*)d_in[4];
  const float* Wo   = (const float*)d_in[5];
  const float* bo   = (const float*)d_in[6];
  const float* W1   = (const float*)d_in[7];
  const float* b1   = (const float*)d_in[8];
  const float* W2   = (const float*)d_in[9];
  const float* b2   = (const float*)d_in[10];
  const float* ln1g = (const float*)d_in[11];
  const float* ln1b = (const float*)d_in[12];
  const float* ln2g = (const float*)d_in[13];
  const float* ln2b = (const float*)d_in[14];
  const float* fing = (const float*)d_in[15];
  const float* finb = (const float*)d_in[16];
  const float* Wr   = (const float*)d_in[17];
  const float* br   = (const float*)d_in[18];

  float* logits    = (float*)d_out;
  float* out_depth = logits + (long)NTOK * VV;
  float* out_loss  = out_depth + NTOK;

  char* w = (char*)d_ws;
  float* res            = (float*)w;          w += (long)NTOK * DD * 4;
  float* x              = (float*)w;          w += (long)NTOK * DD * 4;
  unsigned short* hbuf  = (unsigned short*)w; w += (long)NTOK * DD * 2;
  unsigned short* qkvb  = (unsigned short*)w; w += (long)NTOK * 3 * DD * 2;
  unsigned short* obuf  = (unsigned short*)w; w += (long)NTOK * DD * 2;
  unsigned short* ffn1  = (unsigned short*)w; w += (long)NTOK * DFFN * 2;
  float* probs          = (float*)w;          w += (long)NTOK * 3 * 4;
  float* depth_ws       = (float*)w;          w += (long)NTOK * 4;
  unsigned short* WqkvT = (unsigned short*)w; w += (long)LLAYERS * 3 * DD * DD * 2;
  unsigned short* WoT   = (unsigned short*)w; w += (long)LLAYERS * DD * DD * 2;
  unsigned short* W1T   = (unsigned short*)w; w += (long)LLAYERS * DFFN * DD * 2;
  unsigned short* W2T   = (unsigned short*)w; w += (long)LLAYERS * DD * DFFN * 2;
  unsigned short* teb   = (unsigned short*)w; w += (long)VV * DD * 2;

  // ---- weight prep (per launch; ~55 us of pure bandwidth) ----
  for (int l = 0; l < LLAYERS; ++l) {
    wtrans_kernel<<<dim3(3 * DD / 64, DD / 64), 256, 0, stream>>>(
        Wqkv + (long)l * DD * 3 * DD, WqkvT + (long)l * 3 * DD * DD, DD, 3 * DD);
    wtrans_kernel<<<dim3(DD / 64, DD / 64), 256, 0, stream>>>(
        Wo + (long)l * DD * DD, WoT + (long)l * DD * DD, DD, DD);
    wtrans_kernel<<<dim3(DFFN / 64, DD / 64), 256, 0, stream>>>(
        W1 + (long)l * DD * DFFN, W1T + (long)l * DFFN * DD, DD, DFFN);
    wtrans_kernel<<<dim3(DD / 64, DFFN / 64), 256, 0, stream>>>(
        W2 + (long)l * DFFN * DD, W2T + (long)l * DD * DFFN, DFFN, DD);
  }
  bconv_kernel<<<(long)VV * DD / 2048, 256, 0, stream>>>(te, teb);

  embed_kernel<<<NTOK, 256, 0, stream>>>(ids, te, pe, res);
  router_kernel<<<NTOK, 64, 0, stream>>>(res, Wr, br, probs, depth_ws, out_depth);
  router_finalize_kernel<<<1, 256, 0, stream>>>(probs, out_loss);

  for (int step = 0; step < RSTEPS; ++step) {
    hipMemcpyAsync(x, res, (size_t)NTOK * DD * 4, hipMemcpyDeviceToDevice, stream);
    for (int l = 0; l < LLAYERS; ++l) {
      ln_kernel<<<NTOK, 256, 0, stream>>>(x, ln1g + l * DD, ln1b + l * DD, hbuf);
      gemm128_kernel<128, 1, 1, 0, 0><<<dim3(3 * DD / 128, NTOK / 128), 256, 0, stream>>>(
          hbuf, DD, WqkvT + (long)l * 3 * DD * DD, DD, qkvb, 3 * DD,
          bqkv + (long)l * 3 * DD, nullptr, 0, DD);
      attn_kernel<<<dim3(SS / 64, BB * HH), 256, 0, stream>>>(qkvb, obuf);
      gemm128_kernel<64, 0, 1, 1, 0><<<dim3(DD / 64, NTOK / 128), 256, 0, stream>>>(
          obuf, DD, WoT + (long)l * DD * DD, DD, x, DD,
          bo + (long)l * DD, x, DD, DD);
      ln_kernel<<<NTOK, 256, 0, stream>>>(x, ln2g + l * DD, ln2b + l * DD, hbuf);
      gemm128_kernel<128, 1, 1, 0, 1><<<dim3(DFFN / 128, NTOK / 128), 256, 0, stream>>>(
          hbuf, DD, W1T + (long)l * DFFN * DD, DD, ffn1, DFFN,
          b1 + (long)l * DFFN, nullptr, 0, DD);
      gemm128_kernel<64, 0, 1, 1, 0><<<dim3(DD / 64, NTOK / 128), 256, 0, stream>>>(
          ffn1, DFFN, W2T + (long)l * DD * DFFN, DFFN, x, DD,
          b2 + (long)l * DD, x, DD, DFFN);
    }
    select_kernel<<<2048, 256, 0, stream>>>(res, x, depth_ws, step + 1);
  }
  ln_kernel<<<NTOK, 256, 0, stream>>>(res, fing, finb, hbuf);
  gemm128_kernel<128, 0, 0, 0, 0><<<dim3(VV / 128, NTOK / 128), 256, 0, stream>>>(
      hbuf, DD, teb, DD, logits, VV, nullptr, nullptr, 0, DD);
}

// Round 3
// 1544.162 us; speedup vs baseline: 1.9189x; 1.1066x over previous
//
#include <hip/hip_runtime.h>
#include <hip/hip_bf16.h>

#define DD 1024
#define SS 1024
#define BB 2
#define HH 16
#define DFFN 4096
#define LLAYERS 2
#define RSTEPS 3
#define VV 32000
#define NTOK (BB*SS)

typedef __attribute__((ext_vector_type(8))) short s16x8;
typedef __attribute__((ext_vector_type(8))) __bf16 bf16x8;
typedef __attribute__((ext_vector_type(4))) float f32x4;

__device__ __forceinline__ unsigned short f2bf(float f) {
  unsigned int u = __float_as_uint(f);
  u += 0x7FFFu + ((u >> 16) & 1u);
  return (unsigned short)(u >> 16);
}

__device__ __forceinline__ f32x4 mfma16(s16x8 a, s16x8 b, f32x4 c) {
  return __builtin_amdgcn_mfma_f32_16x16x32_bf16(
      __builtin_bit_cast(bf16x8, a), __builtin_bit_cast(bf16x8, b), c, 0, 0, 0);
}

__device__ __forceinline__ void gload16(const unsigned short* g, unsigned short* l) {
  __builtin_amdgcn_global_load_lds(
      (const __attribute__((address_space(1))) unsigned int*)(const void*)g,
      (__attribute__((address_space(3))) unsigned int*)(void*)l, 16, 0, 0);
}

// ---------------- weight prep: f32 [K][N] -> bf16 [N][K] -------------------
__global__ __launch_bounds__(256) void wtrans_kernel(
    const float* __restrict__ src, unsigned short* __restrict__ dst,
    int Kd, int Nd) {
  __shared__ unsigned short t[64][68];
  const int n0 = blockIdx.x * 64, k0 = blockIdx.y * 64;
  const int tid = threadIdx.x;
#pragma unroll
  for (int c = 0; c < 4; ++c) {
    int p = tid + c * 256;
    int kr = p >> 4, nc = (p & 15) * 4;
    float4 v = *(const float4*)(src + (long)(k0 + kr) * Nd + n0 + nc);
    t[nc + 0][kr] = f2bf(v.x);
    t[nc + 1][kr] = f2bf(v.y);
    t[nc + 2][kr] = f2bf(v.z);
    t[nc + 3][kr] = f2bf(v.w);
  }
  __syncthreads();
#pragma unroll
  for (int c = 0; c < 4; ++c) {
    int p = tid + c * 256;
    int nr = p >> 4, kc = (p & 15) * 4;
    ushort4 o;
    o.x = t[nr][kc]; o.y = t[nr][kc + 1]; o.z = t[nr][kc + 2]; o.w = t[nr][kc + 3];
    *(ushort4*)(dst + (long)(n0 + nr) * Kd + k0 + kc) = o;
  }
}

// ---------------- f32 -> bf16 straight convert (te) ------------------------
__global__ __launch_bounds__(256) void bconv_kernel(
    const float* __restrict__ src, unsigned short* __restrict__ dst) {
  long i = ((long)blockIdx.x * 256 + threadIdx.x) * 8;
  float4 v0 = *(const float4*)(src + i);
  float4 v1 = *(const float4*)(src + i + 4);
  ushort4 a, b;
  a.x = f2bf(v0.x); a.y = f2bf(v0.y); a.z = f2bf(v0.z); a.w = f2bf(v0.w);
  b.x = f2bf(v1.x); b.y = f2bf(v1.y); b.z = f2bf(v1.z); b.w = f2bf(v1.w);
  *(ushort4*)(dst + i) = a;
  *(ushort4*)(dst + i + 4) = b;
}

// ---------------- embed ----------------------------------------------------
__global__ __launch_bounds__(256) void embed_kernel(
    const int* __restrict__ ids, const float* __restrict__ te,
    const float* __restrict__ pe, float* __restrict__ res) {
  int row = blockIdx.x;
  int s = row & (SS - 1);
  int id = ids[row];
  int d = threadIdx.x * 4;
  float4 a = *(const float4*)(te + (long)id * DD + d);
  float4 p = *(const float4*)(pe + (long)s * DD + d);
  float4 o; o.x = a.x + p.x; o.y = a.y + p.y; o.z = a.z + p.z; o.w = a.w + p.w;
  *(float4*)(res + (long)row * DD + d) = o;
}

// ---------------- router ---------------------------------------------------
__global__ __launch_bounds__(64) void router_kernel(
    const float* __restrict__ h, const float* __restrict__ Wr,
    const float* __restrict__ br, float* __restrict__ probs,
    float* __restrict__ depth_ws, float* __restrict__ out_depth) {
  int row = blockIdx.x;
  int lane = threadIdx.x;
  const float* hr = h + (long)row * DD;
  float a0 = 0.f, a1 = 0.f, a2 = 0.f;
  for (int i = 0; i < 16; ++i) {
    int d = lane * 16 + i;
    float hv = hr[d];
    a0 += hv * Wr[d * 3 + 0];
    a1 += hv * Wr[d * 3 + 1];
    a2 += hv * Wr[d * 3 + 2];
  }
  for (int off = 32; off; off >>= 1) {
    a0 += __shfl_down(a0, off);
    a1 += __shfl_down(a1, off);
    a2 += __shfl_down(a2, off);
  }
  if (lane == 0) {
    a0 += br[0]; a1 += br[1]; a2 += br[2];
    float m = fmaxf(a0, fmaxf(a1, a2));
    float e0 = expf(a0 - m), e1 = expf(a1 - m), e2 = expf(a2 - m);
    float inv = 1.f / (e0 + e1 + e2);
    probs[row * 3 + 0] = e0 * inv;
    probs[row * 3 + 1] = e1 * inv;
    probs[row * 3 + 2] = e2 * inv;
    int am = 0; float bv = a0;
    if (a1 > bv) { bv = a1; am = 1; }
    if (a2 > bv) { bv = a2; am = 2; }
    float dm = (float)(am + 1);
    depth_ws[row] = dm;
    out_depth[row] = dm;
  }
}

__global__ __launch_bounds__(256) void router_finalize_kernel(
    const float* __restrict__ probs, float* __restrict__ out_loss) {
  __shared__ float red[256][3];
  int t = threadIdx.x;
  float s0 = 0.f, s1 = 0.f, s2 = 0.f;
  for (int r = t; r < NTOK; r += 256) {
    s0 += probs[r * 3 + 0]; s1 += probs[r * 3 + 1]; s2 += probs[r * 3 + 2];
  }
  red[t][0] = s0; red[t][1] = s1; red[t][2] = s2;
  __syncthreads();
  for (int off = 128; off; off >>= 1) {
    if (t < off) {
      red[t][0] += red[t + off][0];
      red[t][1] += red[t + off][1];
      red[t][2] += red[t + off][2];
    }
    __syncthreads();
  }
  if (t == 0) {
    float i0 = red[0][0] / NTOK, i1 = red[0][1] / NTOK, i2 = red[0][2] / NTOK;
    out_loss[0] = (float)RSTEPS * (i0 * i0 + i1 * i1 + i2 * i2);
  }
}

// ---------------- layernorm: f32 in -> bf16 out ----------------------------
__global__ __launch_bounds__(256) void ln_kernel(
    const float* __restrict__ x, const float* __restrict__ g,
    const float* __restrict__ b, unsigned short* __restrict__ y) {
  int row = blockIdx.x;
  int t = threadIdx.x;
  float4 v = *(const float4*)(x + (long)row * DD + t * 4);
  float s = v.x + v.y + v.z + v.w;
  float q = v.x * v.x + v.y * v.y + v.z * v.z + v.w * v.w;
  for (int off = 32; off; off >>= 1) {
    s += __shfl_down(s, off);
    q += __shfl_down(q, off);
  }
  __shared__ float rs[4], rq[4];
  int wave = t >> 6;
  if ((t & 63) == 0) { rs[wave] = s; rq[wave] = q; }
  __syncthreads();
  float S_ = rs[0] + rs[1] + rs[2] + rs[3];
  float Q_ = rq[0] + rq[1] + rq[2] + rq[3];
  float mu = S_ * (1.f / DD);
  float var = Q_ * (1.f / DD) - mu * mu;
  float rstd = rsqrtf(var + 1e-5f);
  int d = t * 4;
  float4 gg = *(const float4*)(g + d);
  float4 bb = *(const float4*)(b + d);
  ushort4 ov;
  ov.x = f2bf((v.x - mu) * rstd * gg.x + bb.x);
  ov.y = f2bf((v.y - mu) * rstd * gg.y + bb.y);
  ov.z = f2bf((v.z - mu) * rstd * gg.z + bb.z);
  ov.w = f2bf((v.w - mu) * rstd * gg.w + bb.w);
  *(ushort4*)(y + (long)row * DD + d) = ov;
}

// ---------------- GEMM (m97 structure + XCD-chunked m-fast swizzle) --------
template<int BN, int CBF16, int BIAS, int RESID, int GELU_ACT>
__global__ __launch_bounds__(256) void gemm128_kernel(
    const unsigned short* __restrict__ A, int lda,
    const unsigned short* __restrict__ Bt, int ldb,
    void* __restrict__ Cv, int ldc,
    const float* __restrict__ bias,
    const float* __restrict__ resid, int ldr,
    int K) {
  constexpr int BM = 128;
  constexpr int WN = BN / 2;
  constexpr int MR = 4;
  constexpr int NR = WN / 16;
  __shared__ unsigned short As[BM * 64];
  __shared__ unsigned short Bs[BN * 64];
  const int tid = threadIdx.x;
  const int lane = tid & 63, wave = tid >> 6;
  const int g = lane >> 4, l16 = lane & 15;
  const int wr = wave >> 1, wc = wave & 1;
  // XCD-chunked, m-fast block order: each XCD owns a contiguous n-range.
  int lin = blockIdx.x + blockIdx.y * gridDim.x;
  int per = (gridDim.x * gridDim.y) >> 3;          // grids are % 8 == 0
  int v = (lin & 7) * per + (lin >> 3);
  const long m0 = (long)(v % gridDim.y) * BM;
  const long n0 = (long)(v / gridDim.y) * BN;
  f32x4 acc[MR][NR] = {};
  for (int k0 = 0; k0 < K; k0 += 64) {
    __syncthreads();
#pragma unroll
    for (int c = 0; c < BM / 32; ++c) {
      int p = tid + c * 256;
      int r = p >> 3, kq = (p & 7) * 8;
      gload16(A + (m0 + r) * (long)lda + k0 + kq, &As[p * 8]);
    }
#pragma unroll
    for (int c = 0; c < BN / 32; ++c) {
      int p = tid + c * 256;
      int r = p >> 3, kq = (p & 7) * 8;
      gload16(Bt + (n0 + r) * (long)ldb + k0 + kq, &Bs[p * 8]);
    }
    __syncthreads();
#pragma unroll
    for (int kk = 0; kk < 2; ++kk) {
      s16x8 af[MR], bf[NR];
#pragma unroll
      for (int m = 0; m < MR; ++m)
        af[m] = *(const s16x8*)&As[(wr * 64 + m * 16 + l16) * 64 + kk * 32 + g * 8];
#pragma unroll
      for (int n = 0; n < NR; ++n)
        bf[n] = *(const s16x8*)&Bs[(wc * WN + n * 16 + l16) * 64 + kk * 32 + g * 8];
#pragma unroll
      for (int m = 0; m < MR; ++m)
#pragma unroll
        for (int n = 0; n < NR; ++n)
          acc[m][n] = mfma16(af[m], bf[n], acc[m][n]);
    }
  }
#pragma unroll
  for (int m = 0; m < MR; ++m) {
#pragma unroll
    for (int n = 0; n < NR; ++n) {
      long row_base = m0 + wr * 64 + m * 16 + g * 4;
      long col = n0 + wc * WN + n * 16 + l16;
      float bv = BIAS ? bias[col] : 0.f;
#pragma unroll
      for (int r = 0; r < 4; ++r) {
        long row = row_base + r;
        float vv = acc[m][n][r] + bv;
        if (RESID) vv += resid[row * (long)ldr + col];
        if (GELU_ACT) {
          float x3 = vv * vv * vv;
          vv = 0.5f * vv * (1.f + tanhf(0.7978845608028654f * (vv + 0.044715f * x3)));
        }
        if (CBF16) ((unsigned short*)Cv)[row * (long)ldc + col] = f2bf(vv);
        else       ((float*)Cv)[row * (long)ldc + col] = vv;
      }
    }
  }
}

// ---------------- V transpose: qkvb V-part -> vt [BH][64][S] ---------------
__global__ __launch_bounds__(256) void vtrans_kernel(
    const unsigned short* __restrict__ qkv, unsigned short* __restrict__ vt) {
  __shared__ unsigned short t[64][72];
  const int s0 = blockIdx.x * 64;
  const int bh = blockIdx.y;
  const int b = bh >> 4, h = bh & 15;
  const int tid = threadIdx.x;
  const long rowbase = (long)b * SS;
#pragma unroll
  for (int c = 0; c < 2; ++c) {
    int p = tid + c * 256;
    int sr = p >> 3, d8 = (p & 7) * 8;
    s16x8 v = *(const s16x8*)(qkv + (rowbase + s0 + sr) * 3072 + 2048 + h * 64 + d8);
#pragma unroll
    for (int j = 0; j < 8; ++j) t[d8 + j][sr] = v[j];
  }
  __syncthreads();
#pragma unroll
  for (int c = 0; c < 2; ++c) {
    int p = tid + c * 256;
    int d = p >> 3, s8 = (p & 7) * 8;
    *(s16x8*)(vt + ((long)bh * 64 + d) * SS + s0 + s8) = *(const s16x8*)&t[d][s8];
  }
}

// ---------------- flash attention v2: swapped QK^T, KVBLK=64, dbuf ---------
// 4 waves; wave owns 16 q-rows (q = qrw + l16, lane-owned). K staged from
// qkvb, V from vt, both via global_load_lds with XOR-swizzled (pre-swizzled
// source) layout: LDS[row][b] = G[row][b ^ ((row&7)<<4)].
__global__ __launch_bounds__(256) void attn_kernel(
    const unsigned short* __restrict__ qkv,   // [NTOK][3072]
    const unsigned short* __restrict__ vt,    // [BH][64][S]
    unsigned short* __restrict__ o) {         // [NTOK][1024]
  __shared__ unsigned short Ks[2][64 * 64];
  __shared__ unsigned short Vs[2][64 * 64];
  __shared__ unsigned short Pl[4][16][72];
  const int qb = blockIdx.x;
  const int bh = blockIdx.y;
  const int b = bh >> 4, h = bh & 15;
  const int tid = threadIdx.x, wave = tid >> 6, lane = tid & 63;
  const int g = lane >> 4, l16 = lane & 15;
  const float NEG_INF = -__builtin_inff();
  const int q0 = qb * 64;
  const int qrw = q0 + wave * 16;
  const long rowbase = (long)b * SS;
  const unsigned short* kbase = qkv + rowbase * 3072 + 1024 + h * 64;
  const unsigned short* vbase = vt + (long)bh * 64 * SS;

  // Q fragments (B-operand of swapped QK^T): Q[q=l16][d=g*8+j]
  const unsigned short* qptr = qkv + (rowbase + qrw + l16) * 3072 + h * 64;
  s16x8 qf0 = *(const s16x8*)(qptr + g * 8);
  s16x8 qf1 = *(const s16x8*)(qptr + 32 + g * 8);

  f32x4 oacc[4] = {};
  float mrun = NEG_INF, lrun = 0.f;

  const int ntile = q0 / 64 + 1;
  const int r_ = tid >> 3;                 // staging row 0..63 (c=0) / same +offset
  const int boff = (tid & 7) * 16;         // staging byte offset in 128B row

  // prologue: stage tile 0 into buf 0
#pragma unroll
  for (int c = 0; c < 2; ++c) {
    int idx = tid + c * 256;
    int r = idx >> 3;
    int bo = (idx & 7) * 16;
    int sw = (bo ^ ((r & 7) << 4)) >> 1;
    gload16(kbase + (long)r * 3072 + sw, &Ks[0][idx * 8]);
    gload16(vbase + (long)r * SS + 0 + sw, &Vs[0][idx * 8]);
  }
  asm volatile("s_waitcnt vmcnt(0)" ::: "memory");
  __syncthreads();

  for (int t = 0; t < ntile; ++t) {
    const int cur = t & 1;
    const int kv0 = t * 64;
    const unsigned short* ks_cur = &Ks[cur][0];
    const unsigned short* vs_cur = &Vs[cur][0];
    // prefetch next tile into other buffer
    if (t + 1 < ntile) {
      const int kvn = kv0 + 64;
#pragma unroll
      for (int c = 0; c < 2; ++c) {
        int idx = tid + c * 256;
        int r = idx >> 3;
        int bo = (idx & 7) * 16;
        int sw = (bo ^ ((r & 7) << 4)) >> 1;
        gload16(kbase + (long)(kvn + r) * 3072 + sw, &Ks[cur ^ 1][idx * 8]);
        gload16(vbase + (long)r * SS + kvn + sw, &Vs[cur ^ 1][idx * 8]);
      }
    }
    // ---- QK^T (swapped): S^T[kv][q], A=K rows, B=Q cols ----
    f32x4 accs[4] = {};
#pragma unroll
    for (int ks = 0; ks < 2; ++ks) {
#pragma unroll
      for (int kvb = 0; kvb < 4; ++kvb) {
        int row = kvb * 16 + l16;
        int bo = ((ks * 64 + g * 16) ^ ((l16 & 7) << 4)) >> 1;
        s16x8 kf = *(const s16x8*)&ks_cur[row * 64 + bo];
        accs[kvb] = mfma16(kf, ks ? qf1 : qf0, accs[kvb]);
      }
    }
    // ---- online softmax: lane owns q = qrw + l16 ----
    const bool needmask = (kv0 + 63 > qrw);
    const int qabs = qrw + l16;
    float sv[4][4];
    float mloc = NEG_INF;
#pragma unroll
    for (int kvb = 0; kvb < 4; ++kvb) {
#pragma unroll
      for (int r = 0; r < 4; ++r) {
        float vv = accs[kvb][r] * 0.125f;
        if (needmask) {
          int kva = kv0 + kvb * 16 + g * 4 + r;
          if (kva > qabs) vv = NEG_INF;
        }
        sv[kvb][r] = vv;
        mloc = fmaxf(mloc, vv);
      }
    }
    mloc = fmaxf(mloc, __shfl_xor(mloc, 16));
    mloc = fmaxf(mloc, __shfl_xor(mloc, 32));
    float mnew = fmaxf(mrun, mloc);
    float alpha = __expf(mrun - mnew);
    float lsum = 0.f;
#pragma unroll
    for (int kvb = 0; kvb < 4; ++kvb) {
      float p0 = __expf(sv[kvb][0] - mnew);
      float p1 = __expf(sv[kvb][1] - mnew);
      float p2 = __expf(sv[kvb][2] - mnew);
      float p3 = __expf(sv[kvb][3] - mnew);
      lsum += (p0 + p1) + (p2 + p3);
      unsigned int w0 = (unsigned)f2bf(p0) | ((unsigned)f2bf(p1) << 16);
      unsigned int w1 = (unsigned)f2bf(p2) | ((unsigned)f2bf(p3) << 16);
      uint2 pw; pw.x = w0; pw.y = w1;
      *(uint2*)&Pl[wave][l16][kvb * 16 + g * 4] = pw;   // P[q=l16][kv contiguous]
    }
    lsum += __shfl_xor(lsum, 16);
    lsum += __shfl_xor(lsum, 32);
    lrun = lrun * alpha + lsum;
    mrun = mnew;
    // rescale O (rows of oacc are q = g*4+r; alpha lives at lane l16 = q)
    float mult[4];
#pragma unroll
    for (int r = 0; r < 4; ++r) mult[r] = __shfl(alpha, g * 4 + r);
#pragma unroll
    for (int nd = 0; nd < 4; ++nd)
#pragma unroll
      for (int r = 0; r < 4; ++r) oacc[nd][r] *= mult[r];
    // ---- PV: O[q][d] += P[q][kv] * V[kv][d] ----
#pragma unroll
    for (int kh = 0; kh < 2; ++kh) {
      s16x8 pa = *(const s16x8*)&Pl[wave][l16][kh * 32 + g * 8];
#pragma unroll
      for (int nd = 0; nd < 4; ++nd) {
        int row = nd * 16 + l16;
        int bo = ((kh * 64 + g * 16) ^ ((l16 & 7) << 4)) >> 1;
        s16x8 vf = *(const s16x8*)&vs_cur[row * 64 + bo];
        oacc[nd] = mfma16(pa, vf, oacc[nd]);
      }
    }
    asm volatile("s_waitcnt vmcnt(0)" ::: "memory");
    __syncthreads();
  }
  // epilogue
  unsigned short* ob = o + (rowbase + qrw) * 1024 + h * 64;
#pragma unroll
  for (int r = 0; r < 4; ++r) {
    float lr = __shfl(lrun, g * 4 + r);
    float inv = 1.f / lr;
#pragma unroll
    for (int nd = 0; nd < 4; ++nd)
      ob[(long)(g * 4 + r) * 1024 + nd * 16 + l16] = f2bf(oacc[nd][r] * inv);
  }
  (void)r_; (void)boff;
}

// ---------------- select ---------------------------------------------------
__global__ __launch_bounds__(256) void select_kernel(
    float* __restrict__ res, const float* __restrict__ x,
    const float* __restrict__ depth_ws, int step1) {
  long i = (long)blockIdx.x * blockDim.x + threadIdx.x;
  int tok = (int)(i >> 8);
  if (depth_ws[tok] >= (float)step1)
    ((float4*)res)[i] = ((const float4*)x)[i];
}

extern "C" void kernel_launch(void* const* d_in, const int* in_sizes, int n_in,
                              void* d_out, int out_size, void* d_ws, size_t ws_size,
                              hipStream_t stream) {
  (void)in_sizes; (void)n_in; (void)out_size; (void)ws_size;
  const int*   ids  = (const int*)d_in[0];
  const float* te   = (const float*)d_in[1];
  const float* pe   = (const float*)d_in[2];
  const float* Wqkv = (const float*)d_in[3];
  const float* bqkv = (const float*)d_in[4];
  const float* Wo   = (const float*)d_in[5];
  const float* bo   = (const float*)d_in[6];
  const float* W1   = (const float*)d_in[7];
  const float* b1   = (const float*)d_in[8];
  const float* W2   = (const float*)d_in[9];
  const float* b2   = (const float*)d_in[10];
  const float* ln1g = (const float*)d_in[11];
  const float* ln1b = (const float*)d_in[12];
  const float* ln2g = (const float*)d_in[13];
  const float* ln2b = (const float*)d_in[14];
  const float* fing = (const float*)d_in[15];
  const float* finb = (const float*)d_in[16];
  const float* Wr   = (const float*)d_in[17];
  const float* br   = (const float*)d_in[18];

  float* logits    = (float*)d_out;
  float* out_depth = logits + (long)NTOK * VV;
  float* out_loss  = out_depth + NTOK;

  char* w = (char*)d_ws;
  float* res            = (float*)w;          w += (long)NTOK * DD * 4;
  float* x              = (float*)w;          w += (long)NTOK * DD * 4;
  unsigned short* hbuf  = (unsigned short*)w; w += (long)NTOK * DD * 2;
  unsigned short* qkvb  = (unsigned short*)w; w += (long)NTOK * 3 * DD * 2;
  unsigned short* obuf  = (unsigned short*)w; w += (long)NTOK * DD * 2;
  unsigned short* ffn1  = (unsigned short*)w; w += (long)NTOK * DFFN * 2;
  unsigned short* vtb   = (unsigned short*)w; w += (long)BB * HH * 64 * SS * 2;
  float* probs          = (float*)w;          w += (long)NTOK * 3 * 4;
  float* depth_ws       = (float*)w;          w += (long)NTOK * 4;
  unsigned short* WqkvT = (unsigned short*)w; w += (long)LLAYERS * 3 * DD * DD * 2;
  unsigned short* WoT   = (unsigned short*)w; w += (long)LLAYERS * DD * DD * 2;
  unsigned short* W1T   = (unsigned short*)w; w += (long)LLAYERS * DFFN * DD * 2;
  unsigned short* W2T   = (unsigned short*)w; w += (long)LLAYERS * DD * DFFN * 2;
  unsigned short* teb   = (unsigned short*)w; w += (long)VV * DD * 2;

  for (int l = 0; l < LLAYERS; ++l) {
    wtrans_kernel<<<dim3(3 * DD / 64, DD / 64), 256, 0, stream>>>(
        Wqkv + (long)l * DD * 3 * DD, WqkvT + (long)l * 3 * DD * DD, DD, 3 * DD);
    wtrans_kernel<<<dim3(DD / 64, DD / 64), 256, 0, stream>>>(
        Wo + (long)l * DD * DD, WoT + (long)l * DD * DD, DD, DD);
    wtrans_kernel<<<dim3(DFFN / 64, DD / 64), 256, 0, stream>>>(
        W1 + (long)l * DD * DFFN, W1T + (long)l * DFFN * DD, DD, DFFN);
    wtrans_kernel<<<dim3(DD / 64, DFFN / 64), 256, 0, stream>>>(
        W2 + (long)l * DFFN * DD, W2T + (long)l * DD * DFFN, DFFN, DD);
  }
  bconv_kernel<<<(long)VV * DD / 2048, 256, 0, stream>>>(te, teb);

  embed_kernel<<<NTOK, 256, 0, stream>>>(ids, te, pe, res);
  router_kernel<<<NTOK, 64, 0, stream>>>(res, Wr, br, probs, depth_ws, out_depth);
  router_finalize_kernel<<<1, 256, 0, stream>>>(probs, out_loss);

  for (int step = 0; step < RSTEPS; ++step) {
    for (int l = 0; l < LLAYERS; ++l) {
      const float* xin = (l == 0) ? res : x;
      ln_kernel<<<NTOK, 256, 0, stream>>>(xin, ln1g + l * DD, ln1b + l * DD, hbuf);
      gemm128_kernel<128, 1, 1, 0, 0><<<dim3(3 * DD / 128, NTOK / 128), 256, 0, stream>>>(
          hbuf, DD, WqkvT + (long)l * 3 * DD * DD, DD, qkvb, 3 * DD,
          bqkv + (long)l * 3 * DD, nullptr, 0, DD);
      vtrans_kernel<<<dim3(SS / 64, BB * HH), 256, 0, stream>>>(qkvb, vtb);
      attn_kernel<<<dim3(SS / 64, BB * HH), 256, 0, stream>>>(qkvb, vtb, obuf);
      gemm128_kernel<64, 0, 1, 1, 0><<<dim3(DD / 64, NTOK / 128), 256, 0, stream>>>(
          obuf, DD, WoT + (long)l * DD * DD, DD, x, DD,
          bo + (long)l * DD, xin, DD, DD);
      ln_kernel<<<NTOK, 256, 0, stream>>>(x, ln2g + l * DD, ln2b + l * DD, hbuf);
      gemm128_kernel<128, 1, 1, 0, 1><<<dim3(DFFN / 128, NTOK / 128), 256, 0, stream>>>(
          hbuf, DD, W1T + (long)l * DFFN * DD, DD, ffn1, DFFN,
          b1 + (long)l * DFFN, nullptr, 0, DD);
      gemm128_kernel<64, 0, 1, 1, 0><<<dim3(DD / 64, NTOK / 128), 256, 0, stream>>>(
          ffn1, DFFN, W2T + (long)l * DD * DFFN, DFFN, x, DD,
          b2 + (long)l * DD, x, DD, DFFN);
    }
    select_kernel<<<2048, 256, 0, stream>>>(res, x, depth_ws, step + 1);
  }
  ln_kernel<<<NTOK, 256, 0, stream>>>(res, fing, finb, hbuf);
  gemm128_kernel<128, 0, 0, 0, 0><<<dim3(VV / 128, NTOK / 128), 256, 0, stream>>>(
      hbuf, DD, teb, DD, logits, VV, nullptr, nullptr, 0, DD);
}